// Round 10
// baseline (718.445 us; speedup 1.0000x reference)
//
#include <hip/hip_runtime.h>
#include <hip/hip_fp16.h>

// GCN forward: bucketed partition -> fused {hist+scan+rowptr+dinv+scatter} CSR build ->
// 3x [MFMA fp16 GEMM (BN/ReLU fused staging, dinv prescale) -> CSR SpMM gather
//    (fp16 table, fp32 accum, fused BN-stats, fp16 out)] -> pool+MLP tail.

constexpr int F = 128;
constexpr float BN_EPS = 1e-5f;
constexpr int NB1 = 256;   // partition blocks
constexpr int NBKT = 256;  // buckets of 512 node ids (dst >> 9)

typedef _Float16 f16x8 __attribute__((ext_vector_type(8)));
typedef float f32x4 __attribute__((ext_vector_type(4)));

// ---------------- CSR build K1: per-(block,bucket) histogram ----------------
__global__ __launch_bounds__(256) void part1_k(const int* __restrict__ dst, int* __restrict__ hist, int E) {
  __shared__ int cnt[NBKT];
  int tid = threadIdx.x;
  cnt[tid] = 0;
  __syncthreads();
  int chunk = (E + NB1 - 1) / NB1;
  int s = blockIdx.x * chunk, e = min(s + chunk, E);
  for (int i = s + tid; i < e; i += 256) atomicAdd(&cnt[dst[i] >> 9], 1);
  __syncthreads();
  hist[blockIdx.x * NBKT + tid] = cnt[tid];  // [blk][bkt], coalesced
}

// ---------------- CSR build K2: exclusive scan in (bucket-major, block-minor) order ----
__global__ __launch_bounds__(1024) void part_scan_k(const int* __restrict__ hist, int* __restrict__ base) {
  __shared__ int sh[1024];
  const int t = threadIdx.x;
  const int per = (NBKT * NB1) / 1024;  // 64
  int sum = 0;
  for (int j = 0; j < per; ++j) {
    int i = t * per + j;               // i = b*NB1 + blk
    sum += hist[(i & (NB1 - 1)) * NBKT + (i >> 8)];
  }
  sh[t] = sum;
  __syncthreads();
  for (int off = 1; off < 1024; off <<= 1) {
    int v = (t >= off) ? sh[t - off] : 0;
    __syncthreads();
    sh[t] += v;
    __syncthreads();
  }
  int run = sh[t] - sum;  // exclusive prefix
  for (int j = 0; j < per; ++j) {
    int i = t * per + j;
    int v = hist[(i & (NB1 - 1)) * NBKT + (i >> 8)];
    base[i] = run;  // base laid out i = b*NB1 + blk
    run += v;
  }
}

// ---------------- CSR build K3: partition (src,dst) pairs into buckets ----------------
__global__ __launch_bounds__(256) void part2_k(const int* __restrict__ src, const int* __restrict__ dst,
                                               const int* __restrict__ base, int2* __restrict__ pairbuf, int E) {
  __shared__ int cnt[NBKT];
  __shared__ int baseL[NBKT];
  int tid = threadIdx.x;
  cnt[tid] = 0;
  baseL[tid] = base[tid * NB1 + blockIdx.x];  // base[b][blk] for this blk
  __syncthreads();
  int chunk = (E + NB1 - 1) / NB1;
  int s = blockIdx.x * chunk, e = min(s + chunk, E);
  for (int i = s + tid; i < e; i += 256) {
    int sv = src[i], dv = dst[i];
    int b = dv >> 9;
    int r = atomicAdd(&cnt[b], 1);
    pairbuf[baseL[b] + r] = make_int2(sv, dv);
  }
}

// ---------------- CSR build K4: per-bucket hist+scan -> rowptr/dinv, then scatter -----
// Bucket b owns nodes [b*512,(b+1)*512). Fuses degree hist, prefix scan, rowptr,
// dinv, and the cols scatter in one kernel (replaces hist_k + scanA/B/C + old scat2).
__global__ __launch_bounds__(256) void scat2_k(const int2* __restrict__ pairbuf, const int* __restrict__ base,
                                               int* __restrict__ rowptr, int* __restrict__ cols,
                                               float* __restrict__ dinv, int N, int E) {
  __shared__ int cnt[512];
  __shared__ int cur[512];
  __shared__ int ssum[256];
  const int b = blockIdx.x;
  const int tid = threadIdx.x;
  const int n0 = b << 9;
  cnt[tid] = 0; cnt[tid + 256] = 0;
  __syncthreads();
  const int lo = base[b * NB1];
  const int hi = (b == NBKT - 1) ? E : base[(b + 1) * NB1];
  for (int t = lo + tid; t < hi; t += 256)
    atomicAdd(&cnt[pairbuf[t].y - n0], 1);
  __syncthreads();
  // block scan over 512 counts (2 per thread)
  const int c0 = cnt[2 * tid], c1 = cnt[2 * tid + 1];
  const int s = c0 + c1;
  ssum[tid] = s;
  __syncthreads();
  for (int off = 1; off < 256; off <<= 1) {
    int v = (tid >= off) ? ssum[tid - off] : 0;
    __syncthreads();
    ssum[tid] += v;
    __syncthreads();
  }
  const int excl = ssum[tid] - s;
  const int p0 = lo + excl, p1 = p0 + c0;
  const int node0 = n0 + 2 * tid, node1 = node0 + 1;
  if (node0 < N) { rowptr[node0] = p0; dinv[node0] = rsqrtf((float)c0 + 1.f); }
  if (node1 < N) { rowptr[node1] = p1; dinv[node1] = rsqrtf((float)c1 + 1.f); }
  cur[2 * tid] = p0; cur[2 * tid + 1] = p1;
  if (b == NBKT - 1 && tid == 255) rowptr[N] = E;  // last bucket is past N: lo == E
  __syncthreads();
  for (int t = lo + tid; t < hi; t += 256) {
    int2 pr = pairbuf[t];
    int pos = atomicAdd(&cur[pr.y - n0], 1);
    cols[pos] = pr.x;
  }
}

// ---------------- W transpose + fp16 convert: Wt[l][c][k] = fp16(W[l][k][c]) ----------
__global__ __launch_bounds__(128) void wprep_k(const float* __restrict__ W, __half* __restrict__ Wt) {
  const int b = blockIdx.x;        // b = l*128 + c
  const int k = threadIdx.x;       // 128
  const int l = b >> 7, c = b & 127;
  Wt[(size_t)b * 128 + k] = __float2half(W[(size_t)l * 16384 + k * 128 + c]);
}

// ---------------- BN coefficient prep: scsh[0:128]=scale, [128:256]=shift -------------
__global__ void bnprep_k(const float* __restrict__ stats, const float* __restrict__ gamma,
                         const float* __restrict__ beta, float* __restrict__ scsh,
                         int first, float inv_n) {
  int c = threadIdx.x;  // 128
  if (first) { scsh[c] = 1.f; scsh[128 + c] = 0.f; return; }
  float mu = stats[c] * inv_n;
  float var = stats[128 + c] * inv_n - mu * mu;
  float sc = gamma[c] * rsqrtf(var + BN_EPS);
  scsh[c] = sc;
  scsh[128 + c] = beta[c] - mu * sc;
}

// ---------------- MFMA fp16 GEMM: Ch = fp16( dinv .* (bnrelu(A) @ W) ) ---------------
// A input either fp32 (layer 0: Af) or fp16 (layers 1+: Ah). Tile 64x128, K=128.
// A staged as fp16 in XOR-swizzled LDS (16KB); B-frags read from global Wt (L2-hot).
__global__ __launch_bounds__(256) void gemm_mfma_k(
    const float* __restrict__ Af, const __half* __restrict__ Ah,
    const __half* __restrict__ Wt, __half* __restrict__ Ch,
    const float* __restrict__ scsh, const float* __restrict__ dinv, int n, int dorelu) {
  __shared__ char Al[64 * 256];  // 64 rows x 128 fp16 (256B/row), byte ^= (row&7)<<4
  const int tid = threadIdx.x;
  const int r0 = blockIdx.x * 64;

  // ---- staging: BN/ReLU + fp16 pack + swizzled LDS store ----
  {
    const int row = tid & 63;
    const int cb = tid >> 6;        // 32-col chunk per thread
    const int r = r0 + row;
    const int c0 = cb * 32;
    float xv[32];
    if (Af) {
      if (r < n) {
        const float* ap = Af + (size_t)r * F + c0;
#pragma unroll
        for (int j = 0; j < 8; ++j) {
          float4 v = *(const float4*)(ap + j * 4);
          xv[4 * j] = v.x; xv[4 * j + 1] = v.y; xv[4 * j + 2] = v.z; xv[4 * j + 3] = v.w;
        }
      } else {
#pragma unroll
        for (int j = 0; j < 32; ++j) xv[j] = 0.f;
      }
    } else {
      if (r < n) {
        const int4* ap = (const int4*)(Ah + (size_t)r * F + c0);
#pragma unroll
        for (int j = 0; j < 4; ++j) {
          union { int4 q; __half2 h2[4]; } u;
          u.q = ap[j];
#pragma unroll
          for (int p = 0; p < 4; ++p) {
            float2 f = __half22float2(u.h2[p]);
            xv[8 * j + 2 * p] = f.x;
            xv[8 * j + 2 * p + 1] = f.y;
          }
        }
      } else {
#pragma unroll
        for (int j = 0; j < 32; ++j) xv[j] = 0.f;
      }
    }
    union { __half2 h2[16]; int4 q[4]; } u;
#pragma unroll
    for (int p = 0; p < 16; ++p) {
      float2 sc = *(const float2*)(scsh + c0 + 2 * p);
      float2 sh = *(const float2*)(scsh + 128 + c0 + 2 * p);
      float x0 = fmaf(xv[2 * p], sc.x, sh.x);
      float x1 = fmaf(xv[2 * p + 1], sc.y, sh.y);
      if (dorelu) { x0 = fmaxf(x0, 0.f); x1 = fmaxf(x1, 0.f); }
      u.h2[p] = __floats2half2_rn(x0, x1);
    }
    const int rowb = row * 256;
    const int swz = (row & 7) << 4;
#pragma unroll
    for (int j = 0; j < 4; ++j) {
      int off = (rowb + cb * 64 + j * 16) ^ swz;
      *(int4*)(Al + off) = u.q[j];
    }
  }
  __syncthreads();

  // ---- compute: wave w -> rows w*16..+16, 8 col-tiles, 4 k-chunks ----
  const int w = tid >> 6, l = tid & 63;
  const int arow = w * 16 + (l & 15);
  const int kg = l >> 4;
  f16x8 af[4];
  {
    const int swz = (arow & 7) << 4;
    const int base = arow * 256 + kg * 16;
#pragma unroll
    for (int kc = 0; kc < 4; ++kc)
      af[kc] = *(const f16x8*)(Al + ((base + kc * 64) ^ swz));
  }
  const int orow = r0 + w * 16 + kg * 4;  // this lane's 4 output rows
  float4 dvv = *(const float4*)(dinv + orow);  // dinv carve padded to 256B: safe
  float dvr[4] = {dvv.x, dvv.y, dvv.z, dvv.w};

#pragma unroll
  for (int t = 0; t < 8; ++t) {
    const __half* wp = Wt + ((size_t)(t * 16 + (l & 15)) * 128 + kg * 8);
    f32x4 acc = {0.f, 0.f, 0.f, 0.f};
#pragma unroll
    for (int kc = 0; kc < 4; ++kc) {
      f16x8 bf = *(const f16x8*)(wp + kc * 32);
      acc = __builtin_amdgcn_mfma_f32_16x16x32_f16(af[kc], bf, acc, 0, 0, 0);
    }
    const int ccol = t * 16 + (l & 15);
#pragma unroll
    for (int rr = 0; rr < 4; ++rr) {
      int r = orow + rr;
      if (r < n) Ch[(size_t)r * F + ccol] = __float2half(acc[rr] * dvr[rr]);
    }
  }
}

// ---------------- CSR SpMM aggregate + fused BN-stats ----------------
// Grid-stride wave-per-row; hw is dinv-prescaled fp16.
// out[d] = dinv[d]*(sum hw[s] + hw[d]) + bias, written fp16.
// Per-thread register sum/sumsq of its 2 fixed features, block-combined, 256 atomics.
__global__ __launch_bounds__(256) void spmm_k(const __half* __restrict__ hw, const int* __restrict__ rowptr,
                                              const int* __restrict__ cols, const float* __restrict__ dinv,
                                              const float* __restrict__ bias, __half* __restrict__ outh,
                                              float* __restrict__ stats, int n) {
  const int lane = threadIdx.x & 63;
  const int wv = (blockIdx.x << 2) | (threadIdx.x >> 6);
  const int stride = gridDim.x << 2;
  const __half2* hw2 = (const __half2*)hw;
  const float2 b = ((const float2*)bias)[lane];
  float s0 = 0.f, s1 = 0.f, q0 = 0.f, q1 = 0.f;

  for (int wid = wv; wid < n; wid += stride) {
    float2 vf = __half22float2(hw2[(size_t)wid * 64 + lane]);
    float ax = vf.x, ay = vf.y;  // self-loop term
    int j = rowptr[wid];
    const int e = rowptr[wid + 1];
    for (; j + 8 <= e; j += 8) {
      int c0 = cols[j + 0], c1 = cols[j + 1], c2 = cols[j + 2], c3 = cols[j + 3];
      int c4 = cols[j + 4], c5 = cols[j + 5], c6 = cols[j + 6], c7 = cols[j + 7];
      float2 v0 = __half22float2(hw2[(size_t)c0 * 64 + lane]);
      float2 v1 = __half22float2(hw2[(size_t)c1 * 64 + lane]);
      float2 v2 = __half22float2(hw2[(size_t)c2 * 64 + lane]);
      float2 v3 = __half22float2(hw2[(size_t)c3 * 64 + lane]);
      float2 v4 = __half22float2(hw2[(size_t)c4 * 64 + lane]);
      float2 v5 = __half22float2(hw2[(size_t)c5 * 64 + lane]);
      float2 v6 = __half22float2(hw2[(size_t)c6 * 64 + lane]);
      float2 v7 = __half22float2(hw2[(size_t)c7 * 64 + lane]);
      ax += ((v0.x + v1.x) + (v2.x + v3.x)) + ((v4.x + v5.x) + (v6.x + v7.x));
      ay += ((v0.y + v1.y) + (v2.y + v3.y)) + ((v4.y + v5.y) + (v6.y + v7.y));
    }
    if (j + 4 <= e) {
      int c0 = cols[j + 0], c1 = cols[j + 1], c2 = cols[j + 2], c3 = cols[j + 3];
      float2 v0 = __half22float2(hw2[(size_t)c0 * 64 + lane]);
      float2 v1 = __half22float2(hw2[(size_t)c1 * 64 + lane]);
      float2 v2 = __half22float2(hw2[(size_t)c2 * 64 + lane]);
      float2 v3 = __half22float2(hw2[(size_t)c3 * 64 + lane]);
      ax += (v0.x + v1.x) + (v2.x + v3.x);
      ay += (v0.y + v1.y) + (v2.y + v3.y);
      j += 4;
    }
    for (; j < e; ++j) {
      float2 vv = __half22float2(hw2[(size_t)cols[j] * 64 + lane]);
      ax += vv.x;
      ay += vv.y;
    }
    float di = dinv[wid];
    __half2 oh = __floats2half2_rn(fmaf(di, ax, b.x), fmaf(di, ay, b.y));
    ((__half2*)outh)[(size_t)wid * 64 + lane] = oh;
    float2 of = __half22float2(oh);  // stats of the rounded values the next stage reads
    s0 += of.x; s1 += of.y;
    q0 += of.x * of.x; q1 += of.y * of.y;
  }

  __shared__ float rs0[256], rs1[256], rq0[256], rq1[256];
  rs0[threadIdx.x] = s0; rs1[threadIdx.x] = s1;
  rq0[threadIdx.x] = q0; rq1[threadIdx.x] = q1;
  __syncthreads();
  if (threadIdx.x < 64) {
    const int l = threadIdx.x;
    atomicAdd(&stats[2 * l], rs0[l] + rs0[l + 64] + rs0[l + 128] + rs0[l + 192]);
    atomicAdd(&stats[F + 2 * l], rq0[l] + rq0[l + 64] + rq0[l + 128] + rq0[l + 192]);
  } else if (threadIdx.x < 128) {
    const int l = threadIdx.x - 64;
    atomicAdd(&stats[2 * l + 1], rs1[l] + rs1[l + 64] + rs1[l + 128] + rs1[l + 192]);
    atomicAdd(&stats[F + 2 * l + 1], rq1[l] + rq1[l + 64] + rq1[l + 128] + rq1[l + 192]);
  }
}

// ---------------- fused BN/ReLU + segment mean/max pool + MLP head (fp16 input) -------
__global__ __launch_bounds__(256) void pool_mlp_k(
    const __half* __restrict__ h, const int* __restrict__ batch,
    const float* __restrict__ stats, const float* __restrict__ gamma,
    const float* __restrict__ beta, const float* __restrict__ w1,
    const float* __restrict__ b1, const float* __restrict__ w2,
    const float* __restrict__ b2, float* __restrict__ out,
    int n, float inv_n) {
  __shared__ float psum[4][128];
  __shared__ float pmax[4][128];
  __shared__ float zsh[256];
  __shared__ float part[4][64];
  const int g = blockIdx.x;
  const int tid = threadIdx.x;
  const int wave = tid >> 6, lane = tid & 63;

  int lo = 0, hi = n;
  while (lo < hi) { int m = (lo + hi) >> 1; if (batch[m] < g) lo = m + 1; else hi = m; }
  const int s = lo;
  hi = n;
  while (lo < hi) { int m = (lo + hi) >> 1; if (batch[m] < g + 1) lo = m + 1; else hi = m; }
  const int e = lo;

  const int c = lane * 2;
  float2 st = *(const float2*)(stats + c);
  float2 sq = *(const float2*)(stats + F + c);
  float2 ga = *(const float2*)(gamma + c);
  float2 be = *(const float2*)(beta + c);
  float mu0 = st.x * inv_n, mu1 = st.y * inv_n;
  float sc0 = ga.x * rsqrtf(sq.x * inv_n - mu0 * mu0 + BN_EPS);
  float sc1 = ga.y * rsqrtf(sq.y * inv_n - mu1 * mu1 + BN_EPS);
  float sh0 = be.x - mu0 * sc0;
  float sh1 = be.y - mu1 * sc1;

  const __half2* h2 = (const __half2*)h;
  float sum0 = 0.f, sum1 = 0.f, mx0 = 0.f, mx1 = 0.f;  // post-ReLU >= 0
#pragma unroll 2
  for (int r = s + wave; r < e; r += 4) {
    float2 v = __half22float2(h2[(size_t)r * 64 + lane]);
    float h0 = fmaxf(fmaf(v.x, sc0, sh0), 0.f);
    float h1 = fmaxf(fmaf(v.y, sc1, sh1), 0.f);
    sum0 += h0; sum1 += h1;
    mx0 = fmaxf(mx0, h0); mx1 = fmaxf(mx1, h1);
  }
  psum[wave][c] = sum0; psum[wave][c + 1] = sum1;
  pmax[wave][c] = mx0;  pmax[wave][c + 1] = mx1;
  __syncthreads();

  if (tid < 128) {
    float sm = psum[0][tid] + psum[1][tid] + psum[2][tid] + psum[3][tid];
    float mx = fmaxf(fmaxf(pmax[0][tid], pmax[1][tid]), fmaxf(pmax[2][tid], pmax[3][tid]));
    float ic = (e > s) ? 1.0f / (float)(e - s) : 0.f;
    zsh[tid] = sm * ic;
    zsh[128 + tid] = mx;
  }
  __syncthreads();

  {
    const int j = lane, q = wave;
    float acc = 0.f;
    const float* wq = w1 + (size_t)q * 64 * 64 + j;
#pragma unroll 8
    for (int i = 0; i < 64; ++i) acc = fmaf(zsh[q * 64 + i], wq[(size_t)i * 64], acc);
    part[q][j] = acc;
  }
  __syncthreads();

  if (tid < 64) {
    float hid = part[0][tid] + part[1][tid] + part[2][tid] + part[3][tid] + b1[tid];
    hid = fmaxf(hid, 0.f) * w2[tid];
    for (int off = 32; off > 0; off >>= 1) hid += __shfl_down(hid, off);
    if (tid == 0) out[g] = hid + b2[0];
  }
}

extern "C" void kernel_launch(void* const* d_in, const int* in_sizes, int n_in,
                              void* d_out, int out_size, void* d_ws, size_t ws_size,
                              hipStream_t stream) {
  const float* x      = (const float*)d_in[0];
  const int*   ei     = (const int*)d_in[1];
  const int*   batch  = (const int*)d_in[2];
  const float* Ws     = (const float*)d_in[3];
  const float* bsv    = (const float*)d_in[4];
  const float* gammas = (const float*)d_in[5];
  const float* betas  = (const float*)d_in[6];
  const float* w1     = (const float*)d_in[7];
  const float* b1     = (const float*)d_in[8];
  const float* w2     = (const float*)d_in[9];
  const float* b2     = (const float*)d_in[10];
  float* out = (float*)d_out;

  const int N = in_sizes[0] / F;          // 100000
  const int E = in_sizes[1] / 2;          // 1600000
  const int G = out_size;                 // 512
  const int L = in_sizes[3] / (F * F);    // 3
  const int* srcp = ei;
  const int* dstp = ei + E;

  char* p = (char*)d_ws;
  auto carve = [&](size_t bytes) {
    char* r = p;
    p += (bytes + 255) & ~(size_t)255;
    return r;
  };
  float*  dinv    = (float*)carve((size_t)N * 4);
  int*    rowptr  = (int*)carve(((size_t)N + 1) * 4);
  int*    colsb   = (int*)carve((size_t)E * 4);
  int*    hist    = (int*)carve((size_t)NB1 * NBKT * 4);
  int*    pbase   = (int*)carve((size_t)NB1 * NBKT * 4);
  int2*   pairbuf = (int2*)carve((size_t)E * 8);
  float*  bnstats = (float*)carve(2 * F * 4);
  float*  scsh    = (float*)carve(2 * F * 4);
  __half* wth     = (__half*)carve((size_t)L * F * F * 2);
  __half* hwh     = (__half*)carve((size_t)N * F * 2);
  __half* aggh    = (__half*)carve((size_t)N * F * 2);
  (void)ws_size; (void)n_in;

  // ---- bucketed CSR build (fused deg/dinv/rowptr) + W fp16 transpose ----
  part1_k<<<NB1, 256, 0, stream>>>(dstp, hist, E);
  part_scan_k<<<1, 1024, 0, stream>>>(hist, pbase);
  part2_k<<<NB1, 256, 0, stream>>>(srcp, dstp, pbase, pairbuf, E);
  scat2_k<<<NBKT, 256, 0, stream>>>(pairbuf, pbase, rowptr, colsb, dinv, N, E);
  wprep_k<<<L * F, 128, 0, stream>>>(Ws, wth);

  // ---- 3 GCN layers ----
  const float invN = 1.0f / (float)N;
  const int gblocks = (N + 63) / 64;
  for (int l = 0; l < L; ++l) {
    const float* ga = (l == 0) ? gammas : gammas + (size_t)(l - 1) * F;
    const float* be = (l == 0) ? betas : betas + (size_t)(l - 1) * F;
    bnprep_k<<<1, 128, 0, stream>>>(bnstats, ga, be, scsh, (l == 0) ? 1 : 0, invN);
    gemm_mfma_k<<<gblocks, 256, 0, stream>>>((l == 0) ? x : nullptr, (l == 0) ? nullptr : aggh,
                                             wth + (size_t)l * F * F, hwh, scsh, dinv, N,
                                             (l == 0) ? 0 : 1);
    hipMemsetAsync(bnstats, 0, 2 * F * 4, stream);
    spmm_k<<<1536, 256, 0, stream>>>(hwh, rowptr, colsb, dinv, bsv + (size_t)l * F,
                                     aggh, bnstats, N);
  }

  // ---- fused BN/ReLU + pooling + MLP head ----
  pool_mlp_k<<<G, 256, 0, stream>>>(aggh, batch, bnstats, gammas + (size_t)(L - 1) * F,
                                    betas + (size_t)(L - 1) * F, w1, b1, w2, b2, out, N, invN);
}

// Round 11
// 623.006 us; speedup vs baseline: 1.1532x; 1.1532x over previous
//
#include <hip/hip_runtime.h>
#include <hip/hip_fp16.h>

// GCN forward: bucketed partition -> fused {hist+scan+rowptr+dinv+scatter} CSR build ->
// 3x [MFMA fp16 GEMM (BN/ReLU fused staging, dinv prescale) -> CSR SpMM gather
//    (fp16 in/out, wave-per-row, fp32 accum) -> fp16 BN stats] -> pool+MLP tail.

constexpr int F = 128;
constexpr float BN_EPS = 1e-5f;
constexpr int NB1 = 256;   // partition blocks
constexpr int NBKT = 256;  // buckets of 512 node ids (dst >> 9)

typedef _Float16 f16x8 __attribute__((ext_vector_type(8)));
typedef float f32x4 __attribute__((ext_vector_type(4)));

// ---------------- CSR build K1: per-(block,bucket) histogram ----------------
__global__ __launch_bounds__(256) void part1_k(const int* __restrict__ dst, int* __restrict__ hist, int E) {
  __shared__ int cnt[NBKT];
  int tid = threadIdx.x;
  cnt[tid] = 0;
  __syncthreads();
  int chunk = (E + NB1 - 1) / NB1;
  int s = blockIdx.x * chunk, e = min(s + chunk, E);
  for (int i = s + tid; i < e; i += 256) atomicAdd(&cnt[dst[i] >> 9], 1);
  __syncthreads();
  hist[blockIdx.x * NBKT + tid] = cnt[tid];  // [blk][bkt], coalesced
}

// ---------------- CSR build K2: exclusive scan in (bucket-major, block-minor) order ----
__global__ __launch_bounds__(1024) void part_scan_k(const int* __restrict__ hist, int* __restrict__ base) {
  __shared__ int sh[1024];
  const int t = threadIdx.x;
  const int per = (NBKT * NB1) / 1024;  // 64
  int sum = 0;
  for (int j = 0; j < per; ++j) {
    int i = t * per + j;               // i = b*NB1 + blk
    sum += hist[(i & (NB1 - 1)) * NBKT + (i >> 8)];
  }
  sh[t] = sum;
  __syncthreads();
  for (int off = 1; off < 1024; off <<= 1) {
    int v = (t >= off) ? sh[t - off] : 0;
    __syncthreads();
    sh[t] += v;
    __syncthreads();
  }
  int run = sh[t] - sum;  // exclusive prefix
  for (int j = 0; j < per; ++j) {
    int i = t * per + j;
    int v = hist[(i & (NB1 - 1)) * NBKT + (i >> 8)];
    base[i] = run;  // base laid out i = b*NB1 + blk
    run += v;
  }
}

// ---------------- CSR build K3: partition (src,dst) pairs into buckets ----------------
__global__ __launch_bounds__(256) void part2_k(const int* __restrict__ src, const int* __restrict__ dst,
                                               const int* __restrict__ base, int2* __restrict__ pairbuf, int E) {
  __shared__ int cnt[NBKT];
  __shared__ int baseL[NBKT];
  int tid = threadIdx.x;
  cnt[tid] = 0;
  baseL[tid] = base[tid * NB1 + blockIdx.x];  // base[b][blk] for this blk
  __syncthreads();
  int chunk = (E + NB1 - 1) / NB1;
  int s = blockIdx.x * chunk, e = min(s + chunk, E);
  for (int i = s + tid; i < e; i += 256) {
    int sv = src[i], dv = dst[i];
    int b = dv >> 9;
    int r = atomicAdd(&cnt[b], 1);
    pairbuf[baseL[b] + r] = make_int2(sv, dv);
  }
}

// ---------------- CSR build K4: per-bucket hist+scan -> rowptr/dinv, then scatter -----
__global__ __launch_bounds__(256) void scat2_k(const int2* __restrict__ pairbuf, const int* __restrict__ base,
                                               int* __restrict__ rowptr, int* __restrict__ cols,
                                               float* __restrict__ dinv, int N, int E) {
  __shared__ int cnt[512];
  __shared__ int cur[512];
  __shared__ int ssum[256];
  const int b = blockIdx.x;
  const int tid = threadIdx.x;
  const int n0 = b << 9;
  cnt[tid] = 0; cnt[tid + 256] = 0;
  __syncthreads();
  const int lo = base[b * NB1];
  const int hi = (b == NBKT - 1) ? E : base[(b + 1) * NB1];
  for (int t = lo + tid; t < hi; t += 256)
    atomicAdd(&cnt[pairbuf[t].y - n0], 1);
  __syncthreads();
  // block scan over 512 counts (2 per thread)
  const int c0 = cnt[2 * tid], c1 = cnt[2 * tid + 1];
  const int s = c0 + c1;
  ssum[tid] = s;
  __syncthreads();
  for (int off = 1; off < 256; off <<= 1) {
    int v = (tid >= off) ? ssum[tid - off] : 0;
    __syncthreads();
    ssum[tid] += v;
    __syncthreads();
  }
  const int excl = ssum[tid] - s;
  const int p0 = lo + excl, p1 = p0 + c0;
  const int node0 = n0 + 2 * tid, node1 = node0 + 1;
  if (node0 < N) { rowptr[node0] = p0; dinv[node0] = rsqrtf((float)c0 + 1.f); }
  if (node1 < N) { rowptr[node1] = p1; dinv[node1] = rsqrtf((float)c1 + 1.f); }
  cur[2 * tid] = p0; cur[2 * tid + 1] = p1;
  if (b == NBKT - 1 && tid == 255) rowptr[N] = E;  // last bucket is past N: lo == E
  __syncthreads();
  for (int t = lo + tid; t < hi; t += 256) {
    int2 pr = pairbuf[t];
    int pos = atomicAdd(&cur[pr.y - n0], 1);
    cols[pos] = pr.x;
  }
}

// ---------------- W transpose + fp16 convert: Wt[l][c][k] = fp16(W[l][k][c]) ----------
__global__ __launch_bounds__(128) void wprep_k(const float* __restrict__ W, __half* __restrict__ Wt) {
  const int b = blockIdx.x;        // b = l*128 + c
  const int k = threadIdx.x;       // 128
  const int l = b >> 7, c = b & 127;
  Wt[(size_t)b * 128 + k] = __float2half(W[(size_t)l * 16384 + k * 128 + c]);
}

// ---------------- BN coefficient prep: scsh[0:128]=scale, [128:256]=shift -------------
__global__ void bnprep_k(const float* __restrict__ stats, const float* __restrict__ gamma,
                         const float* __restrict__ beta, float* __restrict__ scsh,
                         int first, float inv_n) {
  int c = threadIdx.x;  // 128
  if (first) { scsh[c] = 1.f; scsh[128 + c] = 0.f; return; }
  float mu = stats[c] * inv_n;
  float var = stats[128 + c] * inv_n - mu * mu;
  float sc = gamma[c] * rsqrtf(var + BN_EPS);
  scsh[c] = sc;
  scsh[128 + c] = beta[c] - mu * sc;
}

// ---------------- MFMA fp16 GEMM: Ch = fp16( dinv .* (bnrelu(A) @ W) ) ---------------
// A input either fp32 (layer 0: Af) or fp16 (layers 1+: Ah). Tile 64x128, K=128.
__global__ __launch_bounds__(256) void gemm_mfma_k(
    const float* __restrict__ Af, const __half* __restrict__ Ah,
    const __half* __restrict__ Wt, __half* __restrict__ Ch,
    const float* __restrict__ scsh, const float* __restrict__ dinv, int n, int dorelu) {
  __shared__ char Al[64 * 256];  // 64 rows x 128 fp16 (256B/row), byte ^= (row&7)<<4
  const int tid = threadIdx.x;
  const int r0 = blockIdx.x * 64;

  // ---- staging: BN/ReLU + fp16 pack + swizzled LDS store ----
  {
    const int row = tid & 63;
    const int cb = tid >> 6;        // 32-col chunk per thread
    const int r = r0 + row;
    const int c0 = cb * 32;
    float xv[32];
    if (Af) {
      if (r < n) {
        const float* ap = Af + (size_t)r * F + c0;
#pragma unroll
        for (int j = 0; j < 8; ++j) {
          float4 v = *(const float4*)(ap + j * 4);
          xv[4 * j] = v.x; xv[4 * j + 1] = v.y; xv[4 * j + 2] = v.z; xv[4 * j + 3] = v.w;
        }
      } else {
#pragma unroll
        for (int j = 0; j < 32; ++j) xv[j] = 0.f;
      }
    } else {
      if (r < n) {
        const int4* ap = (const int4*)(Ah + (size_t)r * F + c0);
#pragma unroll
        for (int j = 0; j < 4; ++j) {
          union { int4 q; __half2 h2[4]; } u;
          u.q = ap[j];
#pragma unroll
          for (int p = 0; p < 4; ++p) {
            float2 f = __half22float2(u.h2[p]);
            xv[8 * j + 2 * p] = f.x;
            xv[8 * j + 2 * p + 1] = f.y;
          }
        }
      } else {
#pragma unroll
        for (int j = 0; j < 32; ++j) xv[j] = 0.f;
      }
    }
    union { __half2 h2[16]; int4 q[4]; } u;
#pragma unroll
    for (int p = 0; p < 16; ++p) {
      float2 sc = *(const float2*)(scsh + c0 + 2 * p);
      float2 sh = *(const float2*)(scsh + 128 + c0 + 2 * p);
      float x0 = fmaf(xv[2 * p], sc.x, sh.x);
      float x1 = fmaf(xv[2 * p + 1], sc.y, sh.y);
      if (dorelu) { x0 = fmaxf(x0, 0.f); x1 = fmaxf(x1, 0.f); }
      u.h2[p] = __floats2half2_rn(x0, x1);
    }
    const int rowb = row * 256;
    const int swz = (row & 7) << 4;
#pragma unroll
    for (int j = 0; j < 4; ++j) {
      int off = (rowb + cb * 64 + j * 16) ^ swz;
      *(int4*)(Al + off) = u.q[j];
    }
  }
  __syncthreads();

  // ---- compute: wave w -> rows w*16..+16, 8 col-tiles, 4 k-chunks ----
  const int w = tid >> 6, l = tid & 63;
  const int arow = w * 16 + (l & 15);
  const int kg = l >> 4;
  f16x8 af[4];
  {
    const int swz = (arow & 7) << 4;
    const int base = arow * 256 + kg * 16;
#pragma unroll
    for (int kc = 0; kc < 4; ++kc)
      af[kc] = *(const f16x8*)(Al + ((base + kc * 64) ^ swz));
  }
  const int orow = r0 + w * 16 + kg * 4;  // this lane's 4 output rows
  float4 dvv = *(const float4*)(dinv + orow);  // dinv carve padded to 256B: safe
  float dvr[4] = {dvv.x, dvv.y, dvv.z, dvv.w};

#pragma unroll
  for (int t = 0; t < 8; ++t) {
    const __half* wp = Wt + ((size_t)(t * 16 + (l & 15)) * 128 + kg * 8);
    f32x4 acc = {0.f, 0.f, 0.f, 0.f};
#pragma unroll
    for (int kc = 0; kc < 4; ++kc) {
      f16x8 bf = *(const f16x8*)(wp + kc * 32);
      acc = __builtin_amdgcn_mfma_f32_16x16x32_f16(af[kc], bf, acc, 0, 0, 0);
    }
    const int ccol = t * 16 + (l & 15);
#pragma unroll
    for (int rr = 0; rr < 4; ++rr) {
      int r = orow + rr;
      if (r < n) Ch[(size_t)r * F + ccol] = __float2half(acc[rr] * dvr[rr]);
    }
  }
}

// ---------------- CSR SpMM aggregate: one wave per dst row (max TLP), fp16 in/out -----
// hw is dinv-prescaled fp16: out[d] = dinv[d]*(sum hw[s] + hw[d]) + bias
__global__ __launch_bounds__(256) void spmm_k(const __half* __restrict__ hw, const int* __restrict__ rowptr,
                                              const int* __restrict__ cols, const float* __restrict__ dinv,
                                              const float* __restrict__ bias, __half* __restrict__ outh, int n) {
  int wid = (blockIdx.x * 256 + threadIdx.x) >> 6;
  int lane = threadIdx.x & 63;
  if (wid >= n) return;
  const __half2* hw2 = (const __half2*)hw;
  float2 vf = __half22float2(hw2[(size_t)wid * 64 + lane]);
  float ax = vf.x, ay = vf.y;  // self-loop term
  int j = rowptr[wid];
  const int e = rowptr[wid + 1];
  for (; j + 8 <= e; j += 8) {
    int c0 = cols[j + 0], c1 = cols[j + 1], c2 = cols[j + 2], c3 = cols[j + 3];
    int c4 = cols[j + 4], c5 = cols[j + 5], c6 = cols[j + 6], c7 = cols[j + 7];
    float2 v0 = __half22float2(hw2[(size_t)c0 * 64 + lane]);
    float2 v1 = __half22float2(hw2[(size_t)c1 * 64 + lane]);
    float2 v2 = __half22float2(hw2[(size_t)c2 * 64 + lane]);
    float2 v3 = __half22float2(hw2[(size_t)c3 * 64 + lane]);
    float2 v4 = __half22float2(hw2[(size_t)c4 * 64 + lane]);
    float2 v5 = __half22float2(hw2[(size_t)c5 * 64 + lane]);
    float2 v6 = __half22float2(hw2[(size_t)c6 * 64 + lane]);
    float2 v7 = __half22float2(hw2[(size_t)c7 * 64 + lane]);
    ax += ((v0.x + v1.x) + (v2.x + v3.x)) + ((v4.x + v5.x) + (v6.x + v7.x));
    ay += ((v0.y + v1.y) + (v2.y + v3.y)) + ((v4.y + v5.y) + (v6.y + v7.y));
  }
  if (j + 4 <= e) {
    int c0 = cols[j + 0], c1 = cols[j + 1], c2 = cols[j + 2], c3 = cols[j + 3];
    float2 v0 = __half22float2(hw2[(size_t)c0 * 64 + lane]);
    float2 v1 = __half22float2(hw2[(size_t)c1 * 64 + lane]);
    float2 v2 = __half22float2(hw2[(size_t)c2 * 64 + lane]);
    float2 v3 = __half22float2(hw2[(size_t)c3 * 64 + lane]);
    ax += (v0.x + v1.x) + (v2.x + v3.x);
    ay += (v0.y + v1.y) + (v2.y + v3.y);
    j += 4;
  }
  for (; j < e; ++j) {
    float2 vv = __half22float2(hw2[(size_t)cols[j] * 64 + lane]);
    ax += vv.x;
    ay += vv.y;
  }
  float di = dinv[wid];
  float2 b = ((const float2*)bias)[lane];
  ((__half2*)outh)[(size_t)wid * 64 + lane] =
      __floats2half2_rn(fmaf(di, ax, b.x), fmaf(di, ay, b.y));
}

// ---------------- BN statistics over fp16 agg: sum & sumsq per feature ----------------
__global__ __launch_bounds__(256) void stats16_k(const __half* __restrict__ h, float* __restrict__ stats, int n) {
  __shared__ float rs0[256], rs1[256], rq0[256], rq1[256];
  const int tid = threadIdx.x;
  const int c2 = tid & 63;   // half2 column
  const int rg = tid >> 6;   // 0..3 row-group
  const __half2* h2 = (const __half2*)h;
  float s0 = 0.f, s1 = 0.f, q0 = 0.f, q1 = 0.f;
  for (int r = blockIdx.x * 4 + rg; r < n; r += gridDim.x * 4) {
    float2 v = __half22float2(h2[(size_t)r * 64 + c2]);
    s0 += v.x; s1 += v.y;
    q0 += v.x * v.x; q1 += v.y * v.y;
  }
  rs0[tid] = s0; rs1[tid] = s1; rq0[tid] = q0; rq1[tid] = q1;
  __syncthreads();
  if (tid < 64) {
    atomicAdd(&stats[2 * tid], rs0[tid] + rs0[tid + 64] + rs0[tid + 128] + rs0[tid + 192]);
    atomicAdd(&stats[F + 2 * tid], rq0[tid] + rq0[tid + 64] + rq0[tid + 128] + rq0[tid + 192]);
  } else if (tid < 128) {
    const int l = tid - 64;
    atomicAdd(&stats[2 * l + 1], rs1[l] + rs1[l + 64] + rs1[l + 128] + rs1[l + 192]);
    atomicAdd(&stats[F + 2 * l + 1], rq1[l] + rq1[l + 64] + rq1[l + 128] + rq1[l + 192]);
  }
}

// ---------------- fused BN/ReLU + segment mean/max pool + MLP head (fp16 input) -------
__global__ __launch_bounds__(256) void pool_mlp_k(
    const __half* __restrict__ h, const int* __restrict__ batch,
    const float* __restrict__ stats, const float* __restrict__ gamma,
    const float* __restrict__ beta, const float* __restrict__ w1,
    const float* __restrict__ b1, const float* __restrict__ w2,
    const float* __restrict__ b2, float* __restrict__ out,
    int n, float inv_n) {
  __shared__ float psum[4][128];
  __shared__ float pmax[4][128];
  __shared__ float zsh[256];
  __shared__ float part[4][64];
  const int g = blockIdx.x;
  const int tid = threadIdx.x;
  const int wave = tid >> 6, lane = tid & 63;

  int lo = 0, hi = n;
  while (lo < hi) { int m = (lo + hi) >> 1; if (batch[m] < g) lo = m + 1; else hi = m; }
  const int s = lo;
  hi = n;
  while (lo < hi) { int m = (lo + hi) >> 1; if (batch[m] < g + 1) lo = m + 1; else hi = m; }
  const int e = lo;

  const int c = lane * 2;
  float2 st = *(const float2*)(stats + c);
  float2 sq = *(const float2*)(stats + F + c);
  float2 ga = *(const float2*)(gamma + c);
  float2 be = *(const float2*)(beta + c);
  float mu0 = st.x * inv_n, mu1 = st.y * inv_n;
  float sc0 = ga.x * rsqrtf(sq.x * inv_n - mu0 * mu0 + BN_EPS);
  float sc1 = ga.y * rsqrtf(sq.y * inv_n - mu1 * mu1 + BN_EPS);
  float sh0 = be.x - mu0 * sc0;
  float sh1 = be.y - mu1 * sc1;

  const __half2* h2 = (const __half2*)h;
  float sum0 = 0.f, sum1 = 0.f, mx0 = 0.f, mx1 = 0.f;  // post-ReLU >= 0
#pragma unroll 2
  for (int r = s + wave; r < e; r += 4) {
    float2 v = __half22float2(h2[(size_t)r * 64 + lane]);
    float h0 = fmaxf(fmaf(v.x, sc0, sh0), 0.f);
    float h1 = fmaxf(fmaf(v.y, sc1, sh1), 0.f);
    sum0 += h0; sum1 += h1;
    mx0 = fmaxf(mx0, h0); mx1 = fmaxf(mx1, h1);
  }
  psum[wave][c] = sum0; psum[wave][c + 1] = sum1;
  pmax[wave][c] = mx0;  pmax[wave][c + 1] = mx1;
  __syncthreads();

  if (tid < 128) {
    float sm = psum[0][tid] + psum[1][tid] + psum[2][tid] + psum[3][tid];
    float mx = fmaxf(fmaxf(pmax[0][tid], pmax[1][tid]), fmaxf(pmax[2][tid], pmax[3][tid]));
    float ic = (e > s) ? 1.0f / (float)(e - s) : 0.f;
    zsh[tid] = sm * ic;
    zsh[128 + tid] = mx;
  }
  __syncthreads();

  {
    const int j = lane, q = wave;
    float acc = 0.f;
    const float* wq = w1 + (size_t)q * 64 * 64 + j;
#pragma unroll 8
    for (int i = 0; i < 64; ++i) acc = fmaf(zsh[q * 64 + i], wq[(size_t)i * 64], acc);
    part[q][j] = acc;
  }
  __syncthreads();

  if (tid < 64) {
    float hid = part[0][tid] + part[1][tid] + part[2][tid] + part[3][tid] + b1[tid];
    hid = fmaxf(hid, 0.f) * w2[tid];
    for (int off = 32; off > 0; off >>= 1) hid += __shfl_down(hid, off);
    if (tid == 0) out[g] = hid + b2[0];
  }
}

extern "C" void kernel_launch(void* const* d_in, const int* in_sizes, int n_in,
                              void* d_out, int out_size, void* d_ws, size_t ws_size,
                              hipStream_t stream) {
  const float* x      = (const float*)d_in[0];
  const int*   ei     = (const int*)d_in[1];
  const int*   batch  = (const int*)d_in[2];
  const float* Ws     = (const float*)d_in[3];
  const float* bsv    = (const float*)d_in[4];
  const float* gammas = (const float*)d_in[5];
  const float* betas  = (const float*)d_in[6];
  const float* w1     = (const float*)d_in[7];
  const float* b1     = (const float*)d_in[8];
  const float* w2     = (const float*)d_in[9];
  const float* b2     = (const float*)d_in[10];
  float* out = (float*)d_out;

  const int N = in_sizes[0] / F;          // 100000
  const int E = in_sizes[1] / 2;          // 1600000
  const int G = out_size;                 // 512
  const int L = in_sizes[3] / (F * F);    // 3
  const int* srcp = ei;
  const int* dstp = ei + E;

  char* p = (char*)d_ws;
  auto carve = [&](size_t bytes) {
    char* r = p;
    p += (bytes + 255) & ~(size_t)255;
    return r;
  };
  float*  dinv    = (float*)carve((size_t)N * 4);
  int*    rowptr  = (int*)carve(((size_t)N + 1) * 4);
  int*    colsb   = (int*)carve((size_t)E * 4);
  int*    hist    = (int*)carve((size_t)NB1 * NBKT * 4);
  int*    pbase   = (int*)carve((size_t)NB1 * NBKT * 4);
  int2*   pairbuf = (int2*)carve((size_t)E * 8);
  float*  bnstats = (float*)carve(2 * F * 4);
  float*  scsh    = (float*)carve(2 * F * 4);
  __half* wth     = (__half*)carve((size_t)L * F * F * 2);
  __half* hwh     = (__half*)carve((size_t)N * F * 2);
  __half* aggh    = (__half*)carve((size_t)N * F * 2);
  (void)ws_size; (void)n_in;

  // ---- bucketed CSR build (fused deg/dinv/rowptr) + W fp16 transpose ----
  part1_k<<<NB1, 256, 0, stream>>>(dstp, hist, E);
  part_scan_k<<<1, 1024, 0, stream>>>(hist, pbase);
  part2_k<<<NB1, 256, 0, stream>>>(srcp, dstp, pbase, pairbuf, E);
  scat2_k<<<NBKT, 256, 0, stream>>>(pairbuf, pbase, rowptr, colsb, dinv, N, E);
  wprep_k<<<L * F, 128, 0, stream>>>(Ws, wth);

  // ---- 3 GCN layers ----
  const float invN = 1.0f / (float)N;
  const int gblocks = (N + 63) / 64;
  for (int l = 0; l < L; ++l) {
    const float* ga = (l == 0) ? gammas : gammas + (size_t)(l - 1) * F;
    const float* be = (l == 0) ? betas : betas + (size_t)(l - 1) * F;
    bnprep_k<<<1, 128, 0, stream>>>(bnstats, ga, be, scsh, (l == 0) ? 1 : 0, invN);
    gemm_mfma_k<<<gblocks, 256, 0, stream>>>((l == 0) ? x : nullptr, (l == 0) ? nullptr : aggh,
                                             wth + (size_t)l * F * F, hwh, scsh, dinv, N,
                                             (l == 0) ? 0 : 1);
    hipMemsetAsync(bnstats, 0, 2 * F * 4, stream);
    spmm_k<<<(N * 64 + 255) / 256, 256, 0, stream>>>(hwh, rowptr, colsb, dinv,
                                                     bsv + (size_t)l * F, aggh, N);
    stats16_k<<<512, 256, 0, stream>>>(aggh, bnstats, N);
  }

  // ---- fused BN/ReLU + pooling + MLP head ----
  pool_mlp_k<<<G, 256, 0, stream>>>(aggh, batch, bnstats, gammas + (size_t)(L - 1) * F,
                                    betas + (size_t)(L - 1) * F, w1, b1, w2, b2, out, N, invN);
}

// Round 12
// 582.265 us; speedup vs baseline: 1.2339x; 1.0700x over previous
//
#include <hip/hip_runtime.h>
#include <hip/hip_fp16.h>

// GCN forward: bucketed partition -> fused CSR build -> 3x [MFMA fp16 GEMM (W-tile in
// LDS, BN/ReLU fused staging, dinv prescale) -> CSR SpMM gather (fp16 in/out, wave-per-
// row) -> stats+finalize (ticket pattern, computes scsh, self-zeroing)] -> pool+MLP.

constexpr int F = 128;
constexpr float BN_EPS = 1e-5f;
constexpr int NB1 = 256;   // partition blocks
constexpr int NBKT = 256;  // buckets of 512 node ids (dst >> 9)

typedef _Float16 f16x8 __attribute__((ext_vector_type(8)));
typedef float f32x4 __attribute__((ext_vector_type(4)));

// ---------------- CSR build K1: per-(block,bucket) histogram ----------------
__global__ __launch_bounds__(256) void part1_k(const int* __restrict__ dst, int* __restrict__ hist, int E) {
  __shared__ int cnt[NBKT];
  int tid = threadIdx.x;
  cnt[tid] = 0;
  __syncthreads();
  int chunk = (E + NB1 - 1) / NB1;
  int s = blockIdx.x * chunk, e = min(s + chunk, E);
  for (int i = s + tid; i < e; i += 256) atomicAdd(&cnt[dst[i] >> 9], 1);
  __syncthreads();
  hist[blockIdx.x * NBKT + tid] = cnt[tid];  // [blk][bkt], coalesced
}

// ---------------- CSR build K2: exclusive scan in (bucket-major, block-minor) order ----
__global__ __launch_bounds__(1024) void part_scan_k(const int* __restrict__ hist, int* __restrict__ base) {
  __shared__ int sh[1024];
  const int t = threadIdx.x;
  const int per = (NBKT * NB1) / 1024;  // 64
  int sum = 0;
  for (int j = 0; j < per; ++j) {
    int i = t * per + j;               // i = b*NB1 + blk
    sum += hist[(i & (NB1 - 1)) * NBKT + (i >> 8)];
  }
  sh[t] = sum;
  __syncthreads();
  for (int off = 1; off < 1024; off <<= 1) {
    int v = (t >= off) ? sh[t - off] : 0;
    __syncthreads();
    sh[t] += v;
    __syncthreads();
  }
  int run = sh[t] - sum;  // exclusive prefix
  for (int j = 0; j < per; ++j) {
    int i = t * per + j;
    int v = hist[(i & (NB1 - 1)) * NBKT + (i >> 8)];
    base[i] = run;  // base laid out i = b*NB1 + blk
    run += v;
  }
}

// ---------------- CSR build K3: partition (src,dst) pairs into buckets ----------------
__global__ __launch_bounds__(256) void part2_k(const int* __restrict__ src, const int* __restrict__ dst,
                                               const int* __restrict__ base, int2* __restrict__ pairbuf, int E) {
  __shared__ int cnt[NBKT];
  __shared__ int baseL[NBKT];
  int tid = threadIdx.x;
  cnt[tid] = 0;
  baseL[tid] = base[tid * NB1 + blockIdx.x];  // base[b][blk] for this blk
  __syncthreads();
  int chunk = (E + NB1 - 1) / NB1;
  int s = blockIdx.x * chunk, e = min(s + chunk, E);
  for (int i = s + tid; i < e; i += 256) {
    int sv = src[i], dv = dst[i];
    int b = dv >> 9;
    int r = atomicAdd(&cnt[b], 1);
    pairbuf[baseL[b] + r] = make_int2(sv, dv);
  }
}

// ---------------- CSR build K4: per-bucket hist+scan -> rowptr/dinv, then scatter -----
__global__ __launch_bounds__(256) void scat2_k(const int2* __restrict__ pairbuf, const int* __restrict__ base,
                                               int* __restrict__ rowptr, int* __restrict__ cols,
                                               float* __restrict__ dinv, int N, int E) {
  __shared__ int cnt[512];
  __shared__ int cur[512];
  __shared__ int ssum[256];
  const int b = blockIdx.x;
  const int tid = threadIdx.x;
  const int n0 = b << 9;
  cnt[tid] = 0; cnt[tid + 256] = 0;
  __syncthreads();
  const int lo = base[b * NB1];
  const int hi = (b == NBKT - 1) ? E : base[(b + 1) * NB1];
  for (int t = lo + tid; t < hi; t += 256)
    atomicAdd(&cnt[pairbuf[t].y - n0], 1);
  __syncthreads();
  const int c0 = cnt[2 * tid], c1 = cnt[2 * tid + 1];
  const int s = c0 + c1;
  ssum[tid] = s;
  __syncthreads();
  for (int off = 1; off < 256; off <<= 1) {
    int v = (tid >= off) ? ssum[tid - off] : 0;
    __syncthreads();
    ssum[tid] += v;
    __syncthreads();
  }
  const int excl = ssum[tid] - s;
  const int p0 = lo + excl, p1 = p0 + c0;
  const int node0 = n0 + 2 * tid, node1 = node0 + 1;
  if (node0 < N) { rowptr[node0] = p0; dinv[node0] = rsqrtf((float)c0 + 1.f); }
  if (node1 < N) { rowptr[node1] = p1; dinv[node1] = rsqrtf((float)c1 + 1.f); }
  cur[2 * tid] = p0; cur[2 * tid + 1] = p1;
  if (b == NBKT - 1 && tid == 255) rowptr[N] = E;  // last bucket is past N: lo == E
  __syncthreads();
  for (int t = lo + tid; t < hi; t += 256) {
    int2 pr = pairbuf[t];
    int pos = atomicAdd(&cur[pr.y - n0], 1);
    cols[pos] = pr.x;
  }
}

// ---------------- W transpose + fp16; block 0 also inits scsh/stats/ticket ------------
__global__ __launch_bounds__(128) void wprep_k(const float* __restrict__ W, __half* __restrict__ Wt,
                                               float* __restrict__ scsh, float* __restrict__ stats,
                                               int* __restrict__ ticket) {
  const int b = blockIdx.x;        // b = l*128 + c
  const int k = threadIdx.x;       // 128
  const int l = b >> 7, c = b & 127;
  Wt[(size_t)b * 128 + k] = __float2half(W[(size_t)l * 16384 + k * 128 + c]);
  if (b == 0) {
    scsh[k] = 1.f; scsh[128 + k] = 0.f;   // identity BN for layer 0
    stats[k] = 0.f; stats[128 + k] = 0.f; // ws is re-poisoned every call
    if (k == 0) *ticket = 0;
  }
}

// ---------------- MFMA fp16 GEMM: Ch = fp16( dinv .* (bnrelu(A) @ W) ) ---------------
// A input either fp32 (layer 0: Af) or fp16 (layers 1+: Ah). Tile 64x128, K=128.
// A (16KB) and W (32KB) both staged in XOR-swizzled LDS; B-frags read from LDS.
__global__ __launch_bounds__(256) void gemm_mfma_k(
    const float* __restrict__ Af, const __half* __restrict__ Ah,
    const __half* __restrict__ Wt, __half* __restrict__ Ch,
    const float* __restrict__ scsh, const float* __restrict__ dinv, int n, int dorelu) {
  __shared__ char Al[64 * 256];    // 64 rows x 128 fp16, byte ^= (row&7)<<4
  __shared__ char Wl[128 * 256];   // 128 cols x 128 fp16 (k-major), byte ^= (col&7)<<4
  const int tid = threadIdx.x;
  const int r0 = blockIdx.x * 64;

  // ---- stage W tile: 32KB coalesced global -> swizzled LDS ----
#pragma unroll
  for (int j = 0; j < 8; ++j) {
    int i = j * 256 + tid;          // 16B chunk id (2048 total)
    int c = i >> 4, q = i & 15;
    int4 v = *(const int4*)((const char*)Wt + (size_t)i * 16);
    *(int4*)(Wl + ((c * 256 + q * 16) ^ ((c & 7) << 4))) = v;
  }

  // ---- stage A tile: BN/ReLU + fp16 pack + swizzled LDS store ----
  {
    const int row = tid & 63;
    const int cb = tid >> 6;        // 32-col chunk per thread
    const int r = r0 + row;
    const int c0 = cb * 32;
    float xv[32];
    if (Af) {
      if (r < n) {
        const float* ap = Af + (size_t)r * F + c0;
#pragma unroll
        for (int j = 0; j < 8; ++j) {
          float4 v = *(const float4*)(ap + j * 4);
          xv[4 * j] = v.x; xv[4 * j + 1] = v.y; xv[4 * j + 2] = v.z; xv[4 * j + 3] = v.w;
        }
      } else {
#pragma unroll
        for (int j = 0; j < 32; ++j) xv[j] = 0.f;
      }
    } else {
      if (r < n) {
        const int4* ap = (const int4*)(Ah + (size_t)r * F + c0);
#pragma unroll
        for (int j = 0; j < 4; ++j) {
          union { int4 q; __half2 h2[4]; } u;
          u.q = ap[j];
#pragma unroll
          for (int p = 0; p < 4; ++p) {
            float2 f = __half22float2(u.h2[p]);
            xv[8 * j + 2 * p] = f.x;
            xv[8 * j + 2 * p + 1] = f.y;
          }
        }
      } else {
#pragma unroll
        for (int j = 0; j < 32; ++j) xv[j] = 0.f;
      }
    }
    union { __half2 h2[16]; int4 q[4]; } u;
#pragma unroll
    for (int p = 0; p < 16; ++p) {
      float2 sc = *(const float2*)(scsh + c0 + 2 * p);
      float2 sh = *(const float2*)(scsh + 128 + c0 + 2 * p);
      float x0 = fmaf(xv[2 * p], sc.x, sh.x);
      float x1 = fmaf(xv[2 * p + 1], sc.y, sh.y);
      if (dorelu) { x0 = fmaxf(x0, 0.f); x1 = fmaxf(x1, 0.f); }
      u.h2[p] = __floats2half2_rn(x0, x1);
    }
    const int rowb = row * 256;
    const int swz = (row & 7) << 4;
#pragma unroll
    for (int j = 0; j < 4; ++j) {
      int off = (rowb + cb * 64 + j * 16) ^ swz;
      *(int4*)(Al + off) = u.q[j];
    }
  }
  __syncthreads();

  // ---- compute: wave w -> rows w*16..+16, 8 col-tiles, 4 k-chunks ----
  const int w = tid >> 6, l = tid & 63;
  const int arow = w * 16 + (l & 15);
  const int kg = l >> 4;
  f16x8 af[4];
  {
    const int swz = (arow & 7) << 4;
    const int base = arow * 256 + kg * 16;
#pragma unroll
    for (int kc = 0; kc < 4; ++kc)
      af[kc] = *(const f16x8*)(Al + ((base + kc * 64) ^ swz));
  }
  const int orow = r0 + w * 16 + kg * 4;  // this lane's 4 output rows
  float4 dvv = *(const float4*)(dinv + orow);  // dinv carve padded to 256B: safe
  float dvr[4] = {dvv.x, dvv.y, dvv.z, dvv.w};

#pragma unroll
  for (int t = 0; t < 8; ++t) {
    const int bcol = t * 16 + (l & 15);
    const int bswz = (bcol & 7) << 4;
    const int bbase = bcol * 256 + kg * 16;
    f32x4 acc = {0.f, 0.f, 0.f, 0.f};
#pragma unroll
    for (int kc = 0; kc < 4; ++kc) {
      f16x8 bf = *(const f16x8*)(Wl + ((bbase + kc * 64) ^ bswz));
      acc = __builtin_amdgcn_mfma_f32_16x16x32_f16(af[kc], bf, acc, 0, 0, 0);
    }
    const int ccol = t * 16 + (l & 15);
#pragma unroll
    for (int rr = 0; rr < 4; ++rr) {
      int r = orow + rr;
      if (r < n) Ch[(size_t)r * F + ccol] = __float2half(acc[rr] * dvr[rr]);
    }
  }
}

// ---------------- CSR SpMM aggregate: one wave per dst row (max TLP), fp16 in/out -----
__global__ __launch_bounds__(256) void spmm_k(const __half* __restrict__ hw, const int* __restrict__ rowptr,
                                              const int* __restrict__ cols, const float* __restrict__ dinv,
                                              const float* __restrict__ bias, __half* __restrict__ outh, int n) {
  int wid = (blockIdx.x * 256 + threadIdx.x) >> 6;
  int lane = threadIdx.x & 63;
  if (wid >= n) return;
  const __half2* hw2 = (const __half2*)hw;
  float2 vf = __half22float2(hw2[(size_t)wid * 64 + lane]);
  float ax = vf.x, ay = vf.y;  // self-loop term
  int j = rowptr[wid];
  const int e = rowptr[wid + 1];
  for (; j + 8 <= e; j += 8) {
    int c0 = cols[j + 0], c1 = cols[j + 1], c2 = cols[j + 2], c3 = cols[j + 3];
    int c4 = cols[j + 4], c5 = cols[j + 5], c6 = cols[j + 6], c7 = cols[j + 7];
    float2 v0 = __half22float2(hw2[(size_t)c0 * 64 + lane]);
    float2 v1 = __half22float2(hw2[(size_t)c1 * 64 + lane]);
    float2 v2 = __half22float2(hw2[(size_t)c2 * 64 + lane]);
    float2 v3 = __half22float2(hw2[(size_t)c3 * 64 + lane]);
    float2 v4 = __half22float2(hw2[(size_t)c4 * 64 + lane]);
    float2 v5 = __half22float2(hw2[(size_t)c5 * 64 + lane]);
    float2 v6 = __half22float2(hw2[(size_t)c6 * 64 + lane]);
    float2 v7 = __half22float2(hw2[(size_t)c7 * 64 + lane]);
    ax += ((v0.x + v1.x) + (v2.x + v3.x)) + ((v4.x + v5.x) + (v6.x + v7.x));
    ay += ((v0.y + v1.y) + (v2.y + v3.y)) + ((v4.y + v5.y) + (v6.y + v7.y));
  }
  if (j + 4 <= e) {
    int c0 = cols[j + 0], c1 = cols[j + 1], c2 = cols[j + 2], c3 = cols[j + 3];
    float2 v0 = __half22float2(hw2[(size_t)c0 * 64 + lane]);
    float2 v1 = __half22float2(hw2[(size_t)c1 * 64 + lane]);
    float2 v2 = __half22float2(hw2[(size_t)c2 * 64 + lane]);
    float2 v3 = __half22float2(hw2[(size_t)c3 * 64 + lane]);
    ax += (v0.x + v1.x) + (v2.x + v3.x);
    ay += (v0.y + v1.y) + (v2.y + v3.y);
    j += 4;
  }
  for (; j < e; ++j) {
    float2 vv = __half22float2(hw2[(size_t)cols[j] * 64 + lane]);
    ax += vv.x;
    ay += vv.y;
  }
  float di = dinv[wid];
  float2 b = ((const float2*)bias)[lane];
  ((__half2*)outh)[(size_t)wid * 64 + lane] =
      __floats2half2_rn(fmaf(di, ax, b.x), fmaf(di, ay, b.y));
}

// ---------------- BN stats over fp16 agg + last-block finalize -> scsh ----------------
// Accumulates sum/sumsq via atomics; the last block (ticket) computes scale/shift for
// the NEXT consumer, then zeroes stats and resets the ticket for the next layer.
__global__ __launch_bounds__(256) void stats16_k(const __half* __restrict__ h, float* __restrict__ stats,
                                                 const float* __restrict__ gamma, const float* __restrict__ beta,
                                                 float* __restrict__ scsh, int* __restrict__ ticket,
                                                 int n, float inv_n, int nblocks) {
  __shared__ float rs0[256], rs1[256], rq0[256], rq1[256];
  __shared__ int amlast;
  const int tid = threadIdx.x;
  const int c2 = tid & 63;   // half2 column
  const int rg = tid >> 6;   // 0..3 row-group
  const __half2* h2 = (const __half2*)h;
  float s0 = 0.f, s1 = 0.f, q0 = 0.f, q1 = 0.f;
  for (int r = blockIdx.x * 4 + rg; r < n; r += gridDim.x * 4) {
    float2 v = __half22float2(h2[(size_t)r * 64 + c2]);
    s0 += v.x; s1 += v.y;
    q0 += v.x * v.x; q1 += v.y * v.y;
  }
  rs0[tid] = s0; rs1[tid] = s1; rq0[tid] = q0; rq1[tid] = q1;
  __syncthreads();
  if (tid < 64) {
    atomicAdd(&stats[2 * tid], rs0[tid] + rs0[tid + 64] + rs0[tid + 128] + rs0[tid + 192]);
    atomicAdd(&stats[F + 2 * tid], rq0[tid] + rq0[tid + 64] + rq0[tid + 128] + rq0[tid + 192]);
  } else if (tid < 128) {
    const int l = tid - 64;
    atomicAdd(&stats[2 * l + 1], rs1[l] + rs1[l + 64] + rs1[l + 128] + rs1[l + 192]);
    atomicAdd(&stats[F + 2 * l + 1], rq1[l] + rq1[l + 64] + rq1[l + 128] + rq1[l + 192]);
  }
  __syncthreads();  // all this block's atomics complete
  if (tid == 0) {
    __threadfence();
    amlast = (atomicAdd(ticket, 1) == nblocks - 1);
  }
  __syncthreads();
  if (amlast) {
    if (tid < 128) {
      float s = atomicAdd(&stats[tid], 0.f);        // coherent read of final sums
      float q = atomicAdd(&stats[F + tid], 0.f);
      float mu = s * inv_n;
      float var = q * inv_n - mu * mu;
      float sc = gamma[tid] * rsqrtf(var + BN_EPS);
      scsh[tid] = sc;
      scsh[128 + tid] = beta[tid] - mu * sc;
    }
    __syncthreads();
    if (tid < 128) { stats[tid] = 0.f; stats[F + tid] = 0.f; }  // ready for next layer
    if (tid == 0) *ticket = 0;
  }
}

// ---------------- fused BN/ReLU + segment mean/max pool + MLP head (fp16, scsh) -------
__global__ __launch_bounds__(512) void pool_mlp_k(
    const __half* __restrict__ h, const int* __restrict__ batch,
    const float* __restrict__ scsh, const float* __restrict__ w1,
    const float* __restrict__ b1, const float* __restrict__ w2,
    const float* __restrict__ b2, float* __restrict__ out, int n) {
  __shared__ float psum[8][128];
  __shared__ float pmax[8][128];
  __shared__ float zsh[256];
  __shared__ float part[8][64];
  const int g = blockIdx.x;
  const int tid = threadIdx.x;
  const int wave = tid >> 6, lane = tid & 63;

  int lo = 0, hi = n;
  while (lo < hi) { int m = (lo + hi) >> 1; if (batch[m] < g) lo = m + 1; else hi = m; }
  const int s = lo;
  hi = n;
  while (lo < hi) { int m = (lo + hi) >> 1; if (batch[m] < g + 1) lo = m + 1; else hi = m; }
  const int e = lo;

  const int c = lane * 2;
  float2 sc = *(const float2*)(scsh + c);
  float2 sh = *(const float2*)(scsh + 128 + c);

  const __half2* h2 = (const __half2*)h;
  float sum0 = 0.f, sum1 = 0.f, mx0 = 0.f, mx1 = 0.f;  // post-ReLU >= 0
#pragma unroll 2
  for (int r = s + wave; r < e; r += 8) {
    float2 v = __half22float2(h2[(size_t)r * 64 + lane]);
    float h0 = fmaxf(fmaf(v.x, sc.x, sh.x), 0.f);
    float h1 = fmaxf(fmaf(v.y, sc.y, sh.y), 0.f);
    sum0 += h0; sum1 += h1;
    mx0 = fmaxf(mx0, h0); mx1 = fmaxf(mx1, h1);
  }
  psum[wave][c] = sum0; psum[wave][c + 1] = sum1;
  pmax[wave][c] = mx0;  pmax[wave][c + 1] = mx1;
  __syncthreads();

  if (tid < 128) {
    float sm = 0.f, mx = 0.f;
#pragma unroll
    for (int q = 0; q < 8; ++q) {
      sm += psum[q][tid];
      mx = fmaxf(mx, pmax[q][tid]);
    }
    float ic = (e > s) ? 1.0f / (float)(e - s) : 0.f;
    zsh[tid] = sm * ic;
    zsh[128 + tid] = mx;
  }
  __syncthreads();

  {  // hidden: wave q covers i in [q*32, q*32+32)
    const int j = lane, q = wave;
    float acc = 0.f;
    const float* wq = w1 + (size_t)q * 32 * 64 + j;
#pragma unroll 8
    for (int i = 0; i < 32; ++i) acc = fmaf(zsh[q * 32 + i], wq[(size_t)i * 64], acc);
    part[q][j] = acc;
  }
  __syncthreads();

  if (tid < 64) {
    float hid = b1[tid];
#pragma unroll
    for (int q = 0; q < 8; ++q) hid += part[q][tid];
    hid = fmaxf(hid, 0.f) * w2[tid];
    for (int off = 32; off > 0; off >>= 1) hid += __shfl_down(hid, off);
    if (tid == 0) out[g] = hid + b2[0];
  }
}

extern "C" void kernel_launch(void* const* d_in, const int* in_sizes, int n_in,
                              void* d_out, int out_size, void* d_ws, size_t ws_size,
                              hipStream_t stream) {
  const float* x      = (const float*)d_in[0];
  const int*   ei     = (const int*)d_in[1];
  const int*   batch  = (const int*)d_in[2];
  const float* Ws     = (const float*)d_in[3];
  const float* bsv    = (const float*)d_in[4];
  const float* gammas = (const float*)d_in[5];
  const float* betas  = (const float*)d_in[6];
  const float* w1     = (const float*)d_in[7];
  const float* b1     = (const float*)d_in[8];
  const float* w2     = (const float*)d_in[9];
  const float* b2     = (const float*)d_in[10];
  float* out = (float*)d_out;

  const int N = in_sizes[0] / F;          // 100000
  const int E = in_sizes[1] / 2;          // 1600000
  const int G = out_size;                 // 512
  const int L = in_sizes[3] / (F * F);    // 3
  const int* srcp = ei;
  const int* dstp = ei + E;

  char* p = (char*)d_ws;
  auto carve = [&](size_t bytes) {
    char* r = p;
    p += (bytes + 255) & ~(size_t)255;
    return r;
  };
  float*  dinv    = (float*)carve((size_t)N * 4);
  int*    rowptr  = (int*)carve(((size_t)N + 1) * 4);
  int*    colsb   = (int*)carve((size_t)E * 4);
  int*    hist    = (int*)carve((size_t)NB1 * NBKT * 4);
  int*    pbase   = (int*)carve((size_t)NB1 * NBKT * 4);
  int2*   pairbuf = (int2*)carve((size_t)E * 8);
  float*  bnstats = (float*)carve(2 * F * 4);
  float*  scsh    = (float*)carve(2 * F * 4);
  int*    ticket  = (int*)carve(256);
  __half* wth     = (__half*)carve((size_t)L * F * F * 2);
  __half* hwh     = (__half*)carve((size_t)N * F * 2);
  __half* aggh    = (__half*)carve((size_t)N * F * 2);
  (void)ws_size; (void)n_in;

  // ---- bucketed CSR build (fused deg/dinv/rowptr) + W prep (inits scsh/stats) ----
  part1_k<<<NB1, 256, 0, stream>>>(dstp, hist, E);
  part_scan_k<<<1, 1024, 0, stream>>>(hist, pbase);
  part2_k<<<NB1, 256, 0, stream>>>(srcp, dstp, pbase, pairbuf, E);
  scat2_k<<<NBKT, 256, 0, stream>>>(pairbuf, pbase, rowptr, colsb, dinv, N, E);
  wprep_k<<<L * F, 128, 0, stream>>>(Ws, wth, scsh, bnstats, ticket);

  // ---- 3 GCN layers: gemm -> spmm -> stats+finalize(scsh for next consumer) ----
  const float invN = 1.0f / (float)N;
  const int gblocks = (N + 63) / 64;
  for (int l = 0; l < L; ++l) {
    gemm_mfma_k<<<gblocks, 256, 0, stream>>>((l == 0) ? x : nullptr, (l == 0) ? nullptr : aggh,
                                             wth + (size_t)l * F * F, hwh, scsh, dinv, N,
                                             (l == 0) ? 0 : 1);
    spmm_k<<<(N * 64 + 255) / 256, 256, 0, stream>>>(hwh, rowptr, colsb, dinv,
                                                     bsv + (size_t)l * F, aggh, N);
    stats16_k<<<512, 256, 0, stream>>>(aggh, bnstats, gammas + (size_t)l * F,
                                       betas + (size_t)l * F, scsh, ticket, N, invN, 512);
  }

  // ---- fused BN/ReLU + pooling + MLP head (uses layer-2 scsh) ----
  pool_mlp_k<<<G, 512, 0, stream>>>(aggh, batch, scsh, w1, b1, w2, b2, out, N);
}